// Round 11
// baseline (980.297 us; speedup 1.0000x reference)
//
#include <hip/hip_runtime.h>

#define NN 100000
#define EE 1600000
#define DH 128
#define DO 16
#define NBLK1 98            // ceil(NN/1024)
#define BSH 6               // bucket shift: 64 nodes/bucket
#define NB 1563             // ceil(NN/64)

// ---------------------------------------------------------------------------
// CSR build: zero -> hist -> scan (meta = global exclusive prefix = start) ->
// bstart snapshot -> bucket partition (dst-locality staging) ->
// bucket-local scatter (meta advances to end offsets).
// Final state identical to prior rounds: end(v)=meta[v], beg(v)=meta[v-1],
// deg(v)=end-beg+1 (self-loop).
// ---------------------------------------------------------------------------
__global__ __launch_bounds__(256) void k_zero(int* __restrict__ meta) {
    int v = blockIdx.x * 256 + threadIdx.x;
    if (v < NN) meta[v] = 0;
}

__global__ __launch_bounds__(256) void k_hist(const int* __restrict__ dst,
                                              int* __restrict__ meta) {
    int e = blockIdx.x * 256 + threadIdx.x;
    if (e < EE) atomicAdd(meta + dst[e], 1);
}

__global__ __launch_bounds__(1024) void k_scan1(int* __restrict__ meta,
                                                int* __restrict__ bsum) {
    __shared__ int sm[1024];
    const int t = threadIdx.x;
    const int idx = blockIdx.x * 1024 + t;
    int c = (idx < NN) ? meta[idx] : 0;
    int v = c;
    sm[t] = v;
    __syncthreads();
    for (int off = 1; off < 1024; off <<= 1) {
        int add = (t >= off) ? sm[t - off] : 0;
        __syncthreads();
        v += add;
        sm[t] = v;
        __syncthreads();
    }
    if (t == 1023) bsum[blockIdx.x] = v;
    if (idx < NN) meta[idx] = v - c;   // exclusive within block
}

__global__ __launch_bounds__(128) void k_scan2(int* __restrict__ bsum) {
    __shared__ int sm[128];
    const int t = threadIdx.x;
    int c = (t < NBLK1) ? bsum[t] : 0;
    int v = c;
    sm[t] = v;
    __syncthreads();
    for (int off = 1; off < 128; off <<= 1) {
        int add = (t >= off) ? sm[t - off] : 0;
        __syncthreads();
        v += add;
        sm[t] = v;
        __syncthreads();
    }
    if (t < NBLK1) bsum[t] = v - c;    // exclusive block offsets
}

__global__ __launch_bounds__(256) void k_scan3(int* __restrict__ meta,
                                               const int* __restrict__ bsum) {
    int idx = blockIdx.x * 256 + threadIdx.x;
    if (idx < NN) meta[idx] += bsum[idx >> 10];
}

// snapshot bucket start offsets (= cs range starts) + init bucket cursors
__global__ __launch_bounds__(256) void k_bstart(const int* __restrict__ meta,
                                                int* __restrict__ bstart,
                                                int* __restrict__ bcur) {
    int b = blockIdx.x * 256 + threadIdx.x;
    if (b < NB) {
        int s = meta[b << BSH];
        bstart[b] = s;
        bcur[b] = s;
    } else if (b == NB) {
        bstart[NB] = EE;
    }
}

// partition edges into bucket-contiguous staging (8B appends at cursor fronts)
__global__ __launch_bounds__(256) void kb_part(const int* __restrict__ ei,
                                               int* __restrict__ bcur,
                                               int2* __restrict__ stg) {
    int e = blockIdx.x * 256 + threadIdx.x;
    if (e < EE) {
        int s = ei[e];
        int d = ei[EE + e];
        int pos = atomicAdd(bcur + (d >> BSH), 1);
        stg[pos] = make_int2(s, d);
    }
}

// bucket-local scatter: block b's cs target region is ~4KB -> L1/L2-hot
__global__ __launch_bounds__(256) void kb_scatter(const int2* __restrict__ stg,
                                                  const int* __restrict__ bstart,
                                                  int* __restrict__ meta,
                                                  int* __restrict__ cs) {
    const int beg = bstart[blockIdx.x];
    const int end = bstart[blockIdx.x + 1];
    for (int i = beg + threadIdx.x; i < end; i += 256) {
        int2 p = stg[i];
        int pos = atomicAdd(meta + p.y, 1);
        cs[pos] = p.x;
    }
}

// ---------------------------------------------------------------------------
// GEMM128: out[r] = dis[r] * ( in[r] @ W )   (fp32 VALU)  [R8, measured good]
// W column-HALF tile [128][64] in 32KB LDS; 512 thr = 8 waves; wave does
// 8 rows as 2 half-waves x 4 rows; R3's validated inner loop.
// ---------------------------------------------------------------------------
__global__ __launch_bounds__(512, 4) void k_gemm128(const float* __restrict__ in,
                                                    const float* __restrict__ W,
                                                    const int* __restrict__ meta,
                                                    float* __restrict__ out) {
    __shared__ float Wl[DH * 64];
    const int colbase = (blockIdx.x & 1) * 64;
    for (int i = threadIdx.x * 4; i < DH * 64; i += 512 * 4) {
        const int r = i >> 6;
        const int c = i & 63;
        *(float4*)(Wl + i) = *(const float4*)(W + r * DH + colbase + c);
    }
    __syncthreads();

    const int wid  = threadIdx.x >> 6;   // 0..7
    const int lane = threadIdx.x & 63;
    const int cp   = lane & 31;          // col pair 0..31
    const int rh   = lane >> 5;          // row half 0..1
    const int c2   = cp * 2;

    const int rbw = (blockIdx.x >> 1) * 64 + wid * 8;   // wave's 8-row group
    if (rbw >= NN) return;                               // after sync: safe

    const int r0 = rbw + rh * 4;                         // this half's 4 rows
    const float* x0 = in + (size_t)r0 * DH;

    float2 acc0 = {0.f, 0.f}, acc1 = {0.f, 0.f};
    float2 acc2 = {0.f, 0.f}, acc3 = {0.f, 0.f};

    for (int k = 0; k < DH; k += 4) {
        const float4 a0 = *(const float4*)(x0 + 0 * DH + k);
        const float4 a1 = *(const float4*)(x0 + 1 * DH + k);
        const float4 a2 = *(const float4*)(x0 + 2 * DH + k);
        const float4 a3 = *(const float4*)(x0 + 3 * DH + k);

        const float2 w0 = *(const float2*)(Wl + (k + 0) * 64 + c2);
        const float2 w1 = *(const float2*)(Wl + (k + 1) * 64 + c2);
        const float2 w2 = *(const float2*)(Wl + (k + 2) * 64 + c2);
        const float2 w3 = *(const float2*)(Wl + (k + 3) * 64 + c2);

        acc0.x = fmaf(a0.x, w0.x, acc0.x); acc0.y = fmaf(a0.x, w0.y, acc0.y);
        acc0.x = fmaf(a0.y, w1.x, acc0.x); acc0.y = fmaf(a0.y, w1.y, acc0.y);
        acc0.x = fmaf(a0.z, w2.x, acc0.x); acc0.y = fmaf(a0.z, w2.y, acc0.y);
        acc0.x = fmaf(a0.w, w3.x, acc0.x); acc0.y = fmaf(a0.w, w3.y, acc0.y);

        acc1.x = fmaf(a1.x, w0.x, acc1.x); acc1.y = fmaf(a1.x, w0.y, acc1.y);
        acc1.x = fmaf(a1.y, w1.x, acc1.x); acc1.y = fmaf(a1.y, w1.y, acc1.y);
        acc1.x = fmaf(a1.z, w2.x, acc1.x); acc1.y = fmaf(a1.z, w2.y, acc1.y);
        acc1.x = fmaf(a1.w, w3.x, acc1.x); acc1.y = fmaf(a1.w, w3.y, acc1.y);

        acc2.x = fmaf(a2.x, w0.x, acc2.x); acc2.y = fmaf(a2.x, w0.y, acc2.y);
        acc2.x = fmaf(a2.y, w1.x, acc2.x); acc2.y = fmaf(a2.y, w1.y, acc2.y);
        acc2.x = fmaf(a2.z, w2.x, acc2.x); acc2.y = fmaf(a2.z, w2.y, acc2.y);
        acc2.x = fmaf(a2.w, w3.x, acc2.x); acc2.y = fmaf(a2.w, w3.y, acc2.y);

        acc3.x = fmaf(a3.x, w0.x, acc3.x); acc3.y = fmaf(a3.x, w0.y, acc3.y);
        acc3.x = fmaf(a3.y, w1.x, acc3.x); acc3.y = fmaf(a3.y, w1.y, acc3.y);
        acc3.x = fmaf(a3.z, w2.x, acc3.x); acc3.y = fmaf(a3.z, w2.y, acc3.y);
        acc3.x = fmaf(a3.w, w3.x, acc3.x); acc3.y = fmaf(a3.w, w3.y, acc3.y);
    }

    // epilogue: scale row r by dis[r] = 1/sqrt(deg[r]) and store
    const int bprev = (r0 == 0) ? 0 : meta[r0 - 1];
    const int e0 = meta[r0 + 0];
    const int e1 = meta[r0 + 1];
    const int e2 = meta[r0 + 2];
    const int e3 = meta[r0 + 3];
    const float d0 = 1.0f / sqrtf((float)(e0 - bprev + 1));
    const float d1 = 1.0f / sqrtf((float)(e1 - e0 + 1));
    const float d2 = 1.0f / sqrtf((float)(e2 - e1 + 1));
    const float d3 = 1.0f / sqrtf((float)(e3 - e2 + 1));
    acc0.x *= d0; acc0.y *= d0;
    acc1.x *= d1; acc1.y *= d1;
    acc2.x *= d2; acc2.y *= d2;
    acc3.x *= d3; acc3.y *= d3;

    float* o0 = out + (size_t)r0 * DH + colbase + c2;
    *(float2*)(o0 + 0 * DH) = acc0;
    *(float2*)(o0 + 1 * DH) = acc1;
    *(float2*)(o0 + 2 * DH) = acc2;
    *(float2*)(o0 + 3 * DH) = acc3;
}

// ---------------------------------------------------------------------------
// GEMM16: out[r] = dis[r] * ( in[r] @ W[128,16] )   (input pre-ReLU'd)
// ---------------------------------------------------------------------------
__global__ __launch_bounds__(256) void k_gemm16(const float* __restrict__ in,
                                                const float* __restrict__ W,
                                                const int* __restrict__ meta,
                                                float* __restrict__ out) {
    __shared__ float Wl[DH * DO];
    for (int i = threadIdx.x * 4; i < DH * DO; i += 256 * 4)
        *(float4*)(Wl + i) = *(const float4*)(W + i);
    __syncthreads();

    const int lane = threadIdx.x & 63;
    const int col  = lane & 15;
    const int rsub = lane >> 4;
    const int gw   = blockIdx.x * 4 + (threadIdx.x >> 6);
    const int strd = gridDim.x * 4;

    for (int rb = gw * 4; rb < NN; rb += strd * 4) {
        int row = rb + rsub;
        const float* x0 = in + (size_t)row * DH;
        float acc = 0.f;
        for (int k = 0; k < DH; k += 4) {
            float4 a = *(const float4*)(x0 + k);
            acc = fmaf(a.x, Wl[(k + 0) * DO + col], acc);
            acc = fmaf(a.y, Wl[(k + 1) * DO + col], acc);
            acc = fmaf(a.z, Wl[(k + 2) * DO + col], acc);
            acc = fmaf(a.w, Wl[(k + 3) * DO + col], acc);
        }
        const int e  = meta[row];
        const int bg = (row == 0) ? 0 : meta[row - 1];
        const float dl = 1.0f / sqrtf((float)(e - bg + 1));
        out[(size_t)row * DO + col] = acc * dl;
    }
}

// ---------------------------------------------------------------------------
// agg128: one wave per dst node; msg rows PRE-SCALED by dis[src] -> plain
// row sum. RELU_OUT fuses the next layer's activation into the epilogue.
// out[d] = act( b + dis[d] * ( msg[d] + sum_{s in N(d)} msg[s] ) )
// ---------------------------------------------------------------------------
template <bool RELU_OUT>
__global__ __launch_bounds__(256) void k_agg128(const float* __restrict__ msg,
                                                const int* __restrict__ meta,
                                                const int* __restrict__ cs,
                                                const float* __restrict__ b,
                                                float* __restrict__ out) {
    const int wid  = threadIdx.x >> 6;
    const int lane = threadIdx.x & 63;
    const float2 bb = *(const float2*)(b + lane * 2);
    const int d = blockIdx.x * 4 + wid;
    if (d >= NN) return;
    const int du  = __builtin_amdgcn_readfirstlane(d);
    const int end = meta[du];
    const int beg = (du == 0) ? 0 : meta[du - 1];
    const float dd = 1.0f / sqrtf((float)(end - beg + 1));

    float2 acc = *((const float2*)(msg + (size_t)du * DH) + lane);  // self term

    int j = beg;
    for (; j + 4 <= end; j += 4) {
        int s0 = cs[j], s1 = cs[j + 1], s2 = cs[j + 2], s3 = cs[j + 3];
        float2 v0 = *((const float2*)(msg + (size_t)s0 * DH) + lane);
        float2 v1 = *((const float2*)(msg + (size_t)s1 * DH) + lane);
        float2 v2 = *((const float2*)(msg + (size_t)s2 * DH) + lane);
        float2 v3 = *((const float2*)(msg + (size_t)s3 * DH) + lane);
        acc.x += (v0.x + v1.x) + (v2.x + v3.x);
        acc.y += (v0.y + v1.y) + (v2.y + v3.y);
    }
    for (; j < end; ++j) {
        int s0 = cs[j];
        float2 v0 = *((const float2*)(msg + (size_t)s0 * DH) + lane);
        acc.x += v0.x; acc.y += v0.y;
    }
    float2 o; o.x = bb.x + dd * acc.x; o.y = bb.y + dd * acc.y;
    if (RELU_OUT) { o.x = fmaxf(o.x, 0.f); o.y = fmaxf(o.y, 0.f); }
    *((float2*)(out + (size_t)du * DH) + lane) = o;
}

// ---------------------------------------------------------------------------
// agg16: one thread per output element (NN*16); final layer, no activation
// ---------------------------------------------------------------------------
__global__ __launch_bounds__(256) void k_agg16(const float* __restrict__ msg,
                                               const int* __restrict__ meta,
                                               const int* __restrict__ cs,
                                               const float* __restrict__ b,
                                               float* __restrict__ out) {
    int i = blockIdx.x * 256 + threadIdx.x;
    if (i >= NN * DO) return;
    const int v   = i >> 4;
    const int col = i & 15;
    const int end = meta[v];
    const int beg = (v == 0) ? 0 : meta[v - 1];
    const float dd = 1.0f / sqrtf((float)(end - beg + 1));

    float acc = msg[(size_t)v * DO + col];   // self term (pre-scaled)
    int j = beg;
    for (; j + 4 <= end; j += 4) {
        int s0 = cs[j], s1 = cs[j + 1], s2 = cs[j + 2], s3 = cs[j + 3];
        acc += (msg[(size_t)s0 * DO + col] + msg[(size_t)s1 * DO + col])
             + (msg[(size_t)s2 * DO + col] + msg[(size_t)s3 * DO + col]);
    }
    for (; j < end; ++j) acc += msg[(size_t)cs[j] * DO + col];
    out[i] = b[col] + dd * acc;
}

// ---------------------------------------------------------------------------
extern "C" void kernel_launch(void* const* d_in, const int* in_sizes, int n_in,
                              void* d_out, int out_size, void* d_ws, size_t ws_size,
                              hipStream_t stream) {
    (void)in_sizes; (void)n_in; (void)out_size; (void)ws_size;
    const float* x  = (const float*)d_in[0];
    const int*   ei = (const int*)d_in[1];
    const float* W1 = (const float*)d_in[2];
    const float* b1 = (const float*)d_in[3];
    const float* W2 = (const float*)d_in[4];
    const float* b2 = (const float*)d_in[5];
    const float* W3 = (const float*)d_in[6];
    const float* b3 = (const float*)d_in[7];
    float* out = (float*)d_out;

    // workspace: 109,200,512 B total (<= proven bound). staging/bstart/bcur
    // alias A's region (dead during CSR build; overwritten by gemm later).
    int*   meta = (int*)d_ws;              // [NN]  start->end offset array
    int*   baux = meta + NN;               // [128] block sums
    int*   cs   = baux + 128;              // [EE]  CSR src ids
    float* A    = (float*)(cs + EE);       // [NN*DH] pre-scaled messages
    float* B    = A + (size_t)NN * DH;     // [NN*DH] layer outputs (relu'd)
    float* C    = A;                       // alias: layer-3 msg (A dead then)
    int2*  stg    = (int2*)A;              // alias: [EE] bucket-staged edges
    int*   bstart = (int*)(stg + EE);      // alias: [NB+1]
    int*   bcur   = bstart + NB + 1;       // alias: [NB]

    // ---- CSR build (bucketed scatter) ----
    k_zero   <<<391, 256, 0, stream>>>(meta);
    k_hist   <<<6250, 256, 0, stream>>>(ei + EE, meta);
    k_scan1  <<<NBLK1, 1024, 0, stream>>>(meta, baux);
    k_scan2  <<<1, 128, 0, stream>>>(baux);
    k_scan3  <<<391, 256, 0, stream>>>(meta, baux);
    k_bstart <<<(NB + 256) / 256, 256, 0, stream>>>(meta, bstart, bcur);
    kb_part  <<<6250, 256, 0, stream>>>(ei, bcur, stg);
    kb_scatter<<<NB, 256, 0, stream>>>(stg, bstart, meta, cs);

    // gemm128 grid: 1563 row-blocks (64 rows each) x 2 col-halves
    const int G128 = 1563 * 2;

    // ---- layer 1: A = dis*(x@W1) ; B = relu(b1 + dis*rowsum(A)) ----
    k_gemm128<<<G128, 512, 0, stream>>>(x, W1, meta, A);
    k_agg128<true><<<25000, 256, 0, stream>>>(A, meta, cs, b1, B);

    // ---- layer 2: A = dis*(B@W2) ; B = relu(b2 + dis*rowsum(A)) ----
    k_gemm128<<<G128, 512, 0, stream>>>(B, W2, meta, A);
    k_agg128<true><<<25000, 256, 0, stream>>>(A, meta, cs, b2, B);

    // ---- layer 3: C = dis*(B@W3) ; out = b3 + dis*rowsum(C) ----
    k_gemm16<<<6250, 256, 0, stream>>>(B, W3, meta, C);
    k_agg16<<<6250, 256, 0, stream>>>(C, meta, cs, b3, out);
}

// Round 13
// 771.212 us; speedup vs baseline: 1.2711x; 1.2711x over previous
//
#include <hip/hip_runtime.h>

#define NN 100000
#define EE 1600000
#define DH 128
#define DO 16
#define NBLK1 98            // ceil(NN/1024)
#define SLICE 12500         // NN/8 dst nodes per XCD slice

// ---------------------------------------------------------------------------
// CSR build into ONE cursor array `meta`:
//   zero -> hist (meta[v]=indeg) -> scan (exclusive prefix = start) ->
//   scatter (meta[v] advances to segment end). Afterwards:
//   end(v)=meta[v], beg(v)=v? meta[v-1]:0, deg(v)=end-beg+1 (self-loop).
// ---------------------------------------------------------------------------
__global__ __launch_bounds__(256) void k_zero(int* __restrict__ meta) {
    int v = blockIdx.x * 256 + threadIdx.x;
    if (v < NN) meta[v] = 0;
}

__global__ __launch_bounds__(256) void k_hist(const int* __restrict__ dst,
                                              int* __restrict__ meta) {
    int e = blockIdx.x * 256 + threadIdx.x;
    if (e < EE) atomicAdd(meta + dst[e], 1);
}

__global__ __launch_bounds__(1024) void k_scan1(int* __restrict__ meta,
                                                int* __restrict__ bsum) {
    __shared__ int sm[1024];
    const int t = threadIdx.x;
    const int idx = blockIdx.x * 1024 + t;
    int c = (idx < NN) ? meta[idx] : 0;
    int v = c;
    sm[t] = v;
    __syncthreads();
    for (int off = 1; off < 1024; off <<= 1) {
        int add = (t >= off) ? sm[t - off] : 0;
        __syncthreads();
        v += add;
        sm[t] = v;
        __syncthreads();
    }
    if (t == 1023) bsum[blockIdx.x] = v;
    if (idx < NN) meta[idx] = v - c;   // exclusive within block
}

__global__ __launch_bounds__(128) void k_scan2(int* __restrict__ bsum) {
    __shared__ int sm[128];
    const int t = threadIdx.x;
    int c = (t < NBLK1) ? bsum[t] : 0;
    int v = c;
    sm[t] = v;
    __syncthreads();
    for (int off = 1; off < 128; off <<= 1) {
        int add = (t >= off) ? sm[t - off] : 0;
        __syncthreads();
        v += add;
        sm[t] = v;
        __syncthreads();
    }
    if (t < NBLK1) bsum[t] = v - c;    // exclusive block offsets
}

__global__ __launch_bounds__(256) void k_scan3(int* __restrict__ meta,
                                               const int* __restrict__ bsum) {
    int idx = blockIdx.x * 256 + threadIdx.x;
    if (idx < NN) meta[idx] += bsum[idx >> 10];
}

// ---------------------------------------------------------------------------
// XCD-sliced scatter: blocks with blockIdx&7==g scan ALL edges, scatter only
// dst in [g*SLICE,(g+1)*SLICE). Each cs line is then dirtied by one XCD group
// only (blockIdx%8 ~ XCD round-robin) -> accumulates in that L2, single
// full-line writeback. Fixes the 16x write amplification (105MB -> ~6.4MB+eps)
// measured in R10/R11: lines written from multiple XCDs bounce via HBM.
// Cost: edge list read 8x (~102MB ~ 17us) — cheap vs the write savings.
// ---------------------------------------------------------------------------
__global__ __launch_bounds__(256) void k_scatter(const int* __restrict__ ei,
                                                 int* __restrict__ meta,
                                                 int* __restrict__ cs) {
    const int grp  = blockIdx.x & 7;       // dst slice == intended XCD
    const int bofs = blockIdx.x >> 3;      // rank within slice group
    const int nblk = gridDim.x >> 3;       // blocks per group
    const int lo   = grp * SLICE;
    const int hi   = lo + SLICE;
    for (int base = bofs * 256; base < EE; base += nblk * 256) {
        const int e = base + threadIdx.x;
        if (e < EE) {
            const int d = ei[EE + e];
            if (d >= lo && d < hi) {
                const int pos = atomicAdd(meta + d, 1);
                cs[pos] = ei[e];
            }
        }
    }
}

// ---------------------------------------------------------------------------
// GEMM128: out[r] = dis[r] * ( in[r] @ W )   (fp32 VALU)  [R8, measured good]
// W column-HALF tile [128][64] in 32KB LDS; 512 thr = 8 waves; wave does
// 8 rows as 2 half-waves x 4 rows; R3's validated inner loop.
// ---------------------------------------------------------------------------
__global__ __launch_bounds__(512, 4) void k_gemm128(const float* __restrict__ in,
                                                    const float* __restrict__ W,
                                                    const int* __restrict__ meta,
                                                    float* __restrict__ out) {
    __shared__ float Wl[DH * 64];
    const int colbase = (blockIdx.x & 1) * 64;
    for (int i = threadIdx.x * 4; i < DH * 64; i += 512 * 4) {
        const int r = i >> 6;
        const int c = i & 63;
        *(float4*)(Wl + i) = *(const float4*)(W + r * DH + colbase + c);
    }
    __syncthreads();

    const int wid  = threadIdx.x >> 6;   // 0..7
    const int lane = threadIdx.x & 63;
    const int cp   = lane & 31;          // col pair 0..31
    const int rh   = lane >> 5;          // row half 0..1
    const int c2   = cp * 2;

    const int rbw = (blockIdx.x >> 1) * 64 + wid * 8;   // wave's 8-row group
    if (rbw >= NN) return;                               // after sync: safe

    const int r0 = rbw + rh * 4;                         // this half's 4 rows
    const float* x0 = in + (size_t)r0 * DH;

    float2 acc0 = {0.f, 0.f}, acc1 = {0.f, 0.f};
    float2 acc2 = {0.f, 0.f}, acc3 = {0.f, 0.f};

    for (int k = 0; k < DH; k += 4) {
        const float4 a0 = *(const float4*)(x0 + 0 * DH + k);
        const float4 a1 = *(const float4*)(x0 + 1 * DH + k);
        const float4 a2 = *(const float4*)(x0 + 2 * DH + k);
        const float4 a3 = *(const float4*)(x0 + 3 * DH + k);

        const float2 w0 = *(const float2*)(Wl + (k + 0) * 64 + c2);
        const float2 w1 = *(const float2*)(Wl + (k + 1) * 64 + c2);
        const float2 w2 = *(const float2*)(Wl + (k + 2) * 64 + c2);
        const float2 w3 = *(const float2*)(Wl + (k + 3) * 64 + c2);

        acc0.x = fmaf(a0.x, w0.x, acc0.x); acc0.y = fmaf(a0.x, w0.y, acc0.y);
        acc0.x = fmaf(a0.y, w1.x, acc0.x); acc0.y = fmaf(a0.y, w1.y, acc0.y);
        acc0.x = fmaf(a0.z, w2.x, acc0.x); acc0.y = fmaf(a0.z, w2.y, acc0.y);
        acc0.x = fmaf(a0.w, w3.x, acc0.x); acc0.y = fmaf(a0.w, w3.y, acc0.y);

        acc1.x = fmaf(a1.x, w0.x, acc1.x); acc1.y = fmaf(a1.x, w0.y, acc1.y);
        acc1.x = fmaf(a1.y, w1.x, acc1.x); acc1.y = fmaf(a1.y, w1.y, acc1.y);
        acc1.x = fmaf(a1.z, w2.x, acc1.x); acc1.y = fmaf(a1.z, w2.y, acc1.y);
        acc1.x = fmaf(a1.w, w3.x, acc1.x); acc1.y = fmaf(a1.w, w3.y, acc1.y);

        acc2.x = fmaf(a2.x, w0.x, acc2.x); acc2.y = fmaf(a2.x, w0.y, acc2.y);
        acc2.x = fmaf(a2.y, w1.x, acc2.x); acc2.y = fmaf(a2.y, w1.y, acc2.y);
        acc2.x = fmaf(a2.z, w2.x, acc2.x); acc2.y = fmaf(a2.z, w2.y, acc2.y);
        acc2.x = fmaf(a2.w, w3.x, acc2.x); acc2.y = fmaf(a2.w, w3.y, acc2.y);

        acc3.x = fmaf(a3.x, w0.x, acc3.x); acc3.y = fmaf(a3.x, w0.y, acc3.y);
        acc3.x = fmaf(a3.y, w1.x, acc3.x); acc3.y = fmaf(a3.y, w1.y, acc3.y);
        acc3.x = fmaf(a3.z, w2.x, acc3.x); acc3.y = fmaf(a3.z, w2.y, acc3.y);
        acc3.x = fmaf(a3.w, w3.x, acc3.x); acc3.y = fmaf(a3.w, w3.y, acc3.y);
    }

    // epilogue: scale row r by dis[r] = 1/sqrt(deg[r]) and store
    const int bprev = (r0 == 0) ? 0 : meta[r0 - 1];
    const int e0 = meta[r0 + 0];
    const int e1 = meta[r0 + 1];
    const int e2 = meta[r0 + 2];
    const int e3 = meta[r0 + 3];
    const float d0 = 1.0f / sqrtf((float)(e0 - bprev + 1));
    const float d1 = 1.0f / sqrtf((float)(e1 - e0 + 1));
    const float d2 = 1.0f / sqrtf((float)(e2 - e1 + 1));
    const float d3 = 1.0f / sqrtf((float)(e3 - e2 + 1));
    acc0.x *= d0; acc0.y *= d0;
    acc1.x *= d1; acc1.y *= d1;
    acc2.x *= d2; acc2.y *= d2;
    acc3.x *= d3; acc3.y *= d3;

    float* o0 = out + (size_t)r0 * DH + colbase + c2;
    *(float2*)(o0 + 0 * DH) = acc0;
    *(float2*)(o0 + 1 * DH) = acc1;
    *(float2*)(o0 + 2 * DH) = acc2;
    *(float2*)(o0 + 3 * DH) = acc3;
}

// ---------------------------------------------------------------------------
// GEMM16: out[r] = dis[r] * ( in[r] @ W[128,16] )   (input pre-ReLU'd)
// ---------------------------------------------------------------------------
__global__ __launch_bounds__(256) void k_gemm16(const float* __restrict__ in,
                                                const float* __restrict__ W,
                                                const int* __restrict__ meta,
                                                float* __restrict__ out) {
    __shared__ float Wl[DH * DO];
    for (int i = threadIdx.x * 4; i < DH * DO; i += 256 * 4)
        *(float4*)(Wl + i) = *(const float4*)(W + i);
    __syncthreads();

    const int lane = threadIdx.x & 63;
    const int col  = lane & 15;
    const int rsub = lane >> 4;
    const int gw   = blockIdx.x * 4 + (threadIdx.x >> 6);
    const int strd = gridDim.x * 4;

    for (int rb = gw * 4; rb < NN; rb += strd * 4) {
        int row = rb + rsub;
        const float* x0 = in + (size_t)row * DH;
        float acc = 0.f;
        for (int k = 0; k < DH; k += 4) {
            float4 a = *(const float4*)(x0 + k);
            acc = fmaf(a.x, Wl[(k + 0) * DO + col], acc);
            acc = fmaf(a.y, Wl[(k + 1) * DO + col], acc);
            acc = fmaf(a.z, Wl[(k + 2) * DO + col], acc);
            acc = fmaf(a.w, Wl[(k + 3) * DO + col], acc);
        }
        const int e  = meta[row];
        const int bg = (row == 0) ? 0 : meta[row - 1];
        const float dl = 1.0f / sqrtf((float)(e - bg + 1));
        out[(size_t)row * DO + col] = acc * dl;
    }
}

// ---------------------------------------------------------------------------
// agg128: one wave per dst node; msg rows PRE-SCALED by dis[src] -> plain
// row sum. RELU_OUT fuses the next layer's activation into the epilogue.
// out[d] = act( b + dis[d] * ( msg[d] + sum_{s in N(d)} msg[s] ) )
// ---------------------------------------------------------------------------
template <bool RELU_OUT>
__global__ __launch_bounds__(256) void k_agg128(const float* __restrict__ msg,
                                                const int* __restrict__ meta,
                                                const int* __restrict__ cs,
                                                const float* __restrict__ b,
                                                float* __restrict__ out) {
    const int wid  = threadIdx.x >> 6;
    const int lane = threadIdx.x & 63;
    const float2 bb = *(const float2*)(b + lane * 2);
    const int d = blockIdx.x * 4 + wid;
    if (d >= NN) return;
    const int du  = __builtin_amdgcn_readfirstlane(d);
    const int end = meta[du];
    const int beg = (du == 0) ? 0 : meta[du - 1];
    const float dd = 1.0f / sqrtf((float)(end - beg + 1));

    float2 acc = *((const float2*)(msg + (size_t)du * DH) + lane);  // self term

    int j = beg;
    for (; j + 4 <= end; j += 4) {
        int s0 = cs[j], s1 = cs[j + 1], s2 = cs[j + 2], s3 = cs[j + 3];
        float2 v0 = *((const float2*)(msg + (size_t)s0 * DH) + lane);
        float2 v1 = *((const float2*)(msg + (size_t)s1 * DH) + lane);
        float2 v2 = *((const float2*)(msg + (size_t)s2 * DH) + lane);
        float2 v3 = *((const float2*)(msg + (size_t)s3 * DH) + lane);
        acc.x += (v0.x + v1.x) + (v2.x + v3.x);
        acc.y += (v0.y + v1.y) + (v2.y + v3.y);
    }
    for (; j < end; ++j) {
        int s0 = cs[j];
        float2 v0 = *((const float2*)(msg + (size_t)s0 * DH) + lane);
        acc.x += v0.x; acc.y += v0.y;
    }
    float2 o; o.x = bb.x + dd * acc.x; o.y = bb.y + dd * acc.y;
    if (RELU_OUT) { o.x = fmaxf(o.x, 0.f); o.y = fmaxf(o.y, 0.f); }
    *((float2*)(out + (size_t)du * DH) + lane) = o;
}

// ---------------------------------------------------------------------------
// agg16: one thread per output element (NN*16); final layer, no activation
// ---------------------------------------------------------------------------
__global__ __launch_bounds__(256) void k_agg16(const float* __restrict__ msg,
                                               const int* __restrict__ meta,
                                               const int* __restrict__ cs,
                                               const float* __restrict__ b,
                                               float* __restrict__ out) {
    int i = blockIdx.x * 256 + threadIdx.x;
    if (i >= NN * DO) return;
    const int v   = i >> 4;
    const int col = i & 15;
    const int end = meta[v];
    const int beg = (v == 0) ? 0 : meta[v - 1];
    const float dd = 1.0f / sqrtf((float)(end - beg + 1));

    float acc = msg[(size_t)v * DO + col];   // self term (pre-scaled)
    int j = beg;
    for (; j + 4 <= end; j += 4) {
        int s0 = cs[j], s1 = cs[j + 1], s2 = cs[j + 2], s3 = cs[j + 3];
        acc += (msg[(size_t)s0 * DO + col] + msg[(size_t)s1 * DO + col])
             + (msg[(size_t)s2 * DO + col] + msg[(size_t)s3 * DO + col]);
    }
    for (; j < end; ++j) acc += msg[(size_t)cs[j] * DO + col];
    out[i] = b[col] + dd * acc;
}

// ---------------------------------------------------------------------------
extern "C" void kernel_launch(void* const* d_in, const int* in_sizes, int n_in,
                              void* d_out, int out_size, void* d_ws, size_t ws_size,
                              hipStream_t stream) {
    (void)in_sizes; (void)n_in; (void)out_size; (void)ws_size;
    const float* x  = (const float*)d_in[0];
    const int*   ei = (const int*)d_in[1];
    const float* W1 = (const float*)d_in[2];
    const float* b1 = (const float*)d_in[3];
    const float* W2 = (const float*)d_in[4];
    const float* b2 = (const float*)d_in[5];
    const float* W3 = (const float*)d_in[6];
    const float* b3 = (const float*)d_in[7];
    float* out = (float*)d_out;

    // workspace: 109,200,512 B (<= proven bound)
    int*   meta = (int*)d_ws;              // [NN]  start->end offset array
    int*   baux = meta + NN;               // [128] block sums
    int*   cs   = baux + 128;              // [EE]  CSR src ids
    float* A    = (float*)(cs + EE);       // [NN*DH] pre-scaled messages
    float* B    = A + (size_t)NN * DH;     // [NN*DH] layer outputs (relu'd)
    float* C    = A;                       // alias: layer-3 msg (A dead then)

    // ---- CSR build (XCD-sliced scatter) ----
    k_zero   <<<391, 256, 0, stream>>>(meta);
    k_hist   <<<6250, 256, 0, stream>>>(ei + EE, meta);
    k_scan1  <<<NBLK1, 1024, 0, stream>>>(meta, baux);
    k_scan2  <<<1, 128, 0, stream>>>(baux);
    k_scan3  <<<391, 256, 0, stream>>>(meta, baux);
    k_scatter<<<2048, 256, 0, stream>>>(ei, meta, cs);

    // gemm128 grid: 1563 row-blocks (64 rows each) x 2 col-halves
    const int G128 = 1563 * 2;

    // ---- layer 1: A = dis*(x@W1) ; B = relu(b1 + dis*rowsum(A)) ----
    k_gemm128<<<G128, 512, 0, stream>>>(x, W1, meta, A);
    k_agg128<true><<<25000, 256, 0, stream>>>(A, meta, cs, b1, B);

    // ---- layer 2: A = dis*(B@W2) ; B = relu(b2 + dis*rowsum(A)) ----
    k_gemm128<<<G128, 512, 0, stream>>>(B, W2, meta, A);
    k_agg128<true><<<25000, 256, 0, stream>>>(A, meta, cs, b2, B);

    // ---- layer 3: C = dis*(B@W3) ; out = b3 + dis*rowsum(C) ----
    k_gemm16<<<6250, 256, 0, stream>>>(B, W3, meta, C);
    k_agg16<<<6250, 256, 0, stream>>>(C, meta, cs, b3, out);
}